// Round 11
// baseline (5412.894 us; speedup 1.0000x reference)
//
#include <hip/hip_runtime.h>
#include <hip/hip_bf16.h>
#include <stdint.h>

#define BB 64
#define TT 512
#define DD 512
#define UU 1024
#define G4 4096
#define RETRY_CAP 4096

typedef __bf16 bf16x8 __attribute__((ext_vector_type(8)));
typedef float f32x4 __attribute__((ext_vector_type(4)));
typedef int i32x4 __attribute__((ext_vector_type(4)));
typedef unsigned int u32;
typedef unsigned short u16;
typedef u16 u16x8 __attribute__((ext_vector_type(8)));

__device__ __forceinline__ u16 f2bf(float f) {
  unsigned u = __builtin_bit_cast(unsigned, f);
  return (u16)((u + 0x7FFFu + ((u >> 16) & 1u)) >> 16);  // RTN-even
}

__global__ void cvt_x_kernel(const float* __restrict__ x, u16* __restrict__ xb, int n8) {
  int i = blockIdx.x * blockDim.x + threadIdx.x;
  if (i >= n8) return;
  const float4* p = reinterpret_cast<const float4*>(x) + (size_t)i * 2;
  float4 a = p[0], b = p[1];
  u16x8 o;
  o[0] = f2bf(a.x); o[1] = f2bf(a.y); o[2] = f2bf(a.z); o[3] = f2bf(a.w);
  o[4] = f2bf(b.x); o[5] = f2bf(b.y); o[6] = f2bf(b.z); o[7] = f2bf(b.w);
  reinterpret_cast<u16x8*>(xb)[i] = o;
}

__global__ void zero_kernel(u32* __restrict__ p, int nwords) {
  for (int i = blockIdx.x * blockDim.x + threadIdx.x; i < nwords; i += gridDim.x * blockDim.x) {
    u32 z = 0u;
    const u32* q = p + i;
    asm volatile("global_store_dword %0, %1, off sc0 sc1" :: "v"(q), "v"(z) : "memory");
  }
}

// ---- persistent LSTM: 4-group rotation + cross-slot prefetch, all-register weights ----
// 64 WGs x 512 thr (8 waves). WG owns u [bid*16,+16) for all 4 groups (16 batch
// rows each). Slot j = t*4+G. Pipeline per slot: issue x(j+1); vmcnt(11) (FIFO:
// drains x(j) issued 1 slot ago AND h(j) issued 2 slots ago); x-MFMA; validate
// h tags (tag==t) + retry; h-MFMA; issue h(j+2) into the just-freed bank; zone
// exchange; gates; fire-and-forget tagged store. Transport R7-proven: u32
// ((bf16<<16)|t), sc0 sc1 both sides. W AND R in registers (Wf 32 + Rf 64 +
// H 64 + Ax 16 ~= 230 VGPR, no LDS weight reads -> no bank conflicts).
__launch_bounds__(512, 1)
__global__ void lstm_persist(const float* __restrict__ W, const float* __restrict__ R,
                             const float* __restrict__ bias, const u16* __restrict__ xb,
                             u32* __restrict__ hbuf,  // [4 grp][2 buf][16 row][1024 u] u32
                             float* __restrict__ out) {
  __shared__ float zone[8 * 4 * 64 * 4];  // [wave][gatefrag][lane][reg] f32, 32 KB

  const int tid = threadIdx.x;
  const int w = tid >> 6, lane = tid & 63, l15 = lane & 15, lk = lane >> 4;
  const int u0 = blockIdx.x * 16;
  const int gr = w * 2 + ((lane >> 4) & 1);  // gate row 0..15 (lanes<32 of each wave)
  const int guu = lane & 15;
  const bool gact = lane < 32;

  // ---- persistent weight fragments (R2/R7-verified layout) ----
  bf16x8 Wf[2][4];  // x: k0 = w*64 + s*32 + lk*8
  bf16x8 Rf[4][4];  // h: k0 = w*128 + s*32 + lk*8
  #pragma unroll
  for (int g = 0; g < 4; ++g) {
    const int gcol = g * 1024 + u0 + l15;
    #pragma unroll
    for (int s = 0; s < 2; ++s) {
      const int k0 = w * 64 + s * 32 + lk * 8;
      u16x8 tmp;
      #pragma unroll
      for (int j = 0; j < 8; ++j) tmp[j] = f2bf(W[(size_t)(k0 + j) * G4 + gcol]);
      Wf[s][g] = __builtin_bit_cast(bf16x8, tmp);
    }
    #pragma unroll
    for (int s = 0; s < 4; ++s) {
      const int k0 = w * 128 + s * 32 + lk * 8;
      u16x8 tmp;
      #pragma unroll
      for (int j = 0; j < 8; ++j) tmp[j] = f2bf(R[(size_t)(k0 + j) * G4 + gcol]);
      Rf[s][g] = __builtin_bit_cast(bf16x8, tmp);
    }
  }
  float bv[4];
  #pragma unroll
  for (int g = 0; g < 4; ++g) bv[g] = bias[g * 1024 + u0 + guu];
  float cst[4] = {0.f, 0.f, 0.f, 0.f};  // per-group cell state for (gr, u0+guu)

  // ---- pointers ----
  const u16* xq[4];
  const u32* hrb[4];
  u32* hsb[4];
  #pragma unroll
  for (int g = 0; g < 4; ++g) {
    xq[g] = xb + (size_t)(g * 16 + l15) * (TT * DD) + w * 64 + lk * 8;
    hrb[g] = hbuf + (size_t)(g * 32 + l15) * 1024 + w * 128 + lk * 8;
    hsb[g] = hbuf + (size_t)(g * 32 + gr) * 1024 + u0 + guu;
  }

  asm volatile("s_waitcnt vmcnt(0)" ::: "memory");  // weight loads drained
  __builtin_amdgcn_sched_barrier(0);

  i32x4 HA[8], HB[8];    // h banks (slot parity)
  i32x4 AxA[2], AxB[2];  // x banks

#define XPREF(AX, GN)                                                    \
  asm volatile(                                                          \
      "global_load_dwordx4 %0, %2, off\n\t"                              \
      "global_load_dwordx4 %1, %2, off offset:64"                        \
      : "=&v"(AX[0]), "=&v"(AX[1]) : "v"(xq[GN]));                       \
  xq[GN] += DD

#define HISSUE(HB_, HP)                                                  \
  asm volatile(                                                          \
      "global_load_dwordx4 %0, %8, off sc0 sc1\n\t"                      \
      "global_load_dwordx4 %1, %8, off offset:16 sc0 sc1\n\t"            \
      "global_load_dwordx4 %2, %8, off offset:128 sc0 sc1\n\t"           \
      "global_load_dwordx4 %3, %8, off offset:144 sc0 sc1\n\t"           \
      "global_load_dwordx4 %4, %8, off offset:256 sc0 sc1\n\t"           \
      "global_load_dwordx4 %5, %8, off offset:272 sc0 sc1\n\t"           \
      "global_load_dwordx4 %6, %8, off offset:384 sc0 sc1\n\t"           \
      "global_load_dwordx4 %7, %8, off offset:400 sc0 sc1"               \
      : "=&v"(HB_[0]), "=&v"(HB_[1]), "=&v"(HB_[2]), "=&v"(HB_[3]),      \
        "=&v"(HB_[4]), "=&v"(HB_[5]), "=&v"(HB_[6]), "=&v"(HB_[7])       \
      : "v"(HP) : "memory")

#define VBAD(HB_, badv)                                                  \
  badv = 0;                                                              \
  _Pragma("unroll") for (int i_ = 0; i_ < 8; ++i_)                       \
    _Pragma("unroll") for (int d_ = 0; d_ < 4; ++d_)                     \
      badv |= (HB_[i_][d_] ^ t) & 0xFFFF

  // prime x for slot 0
  XPREF(AxA, 0);

  #pragma unroll 1
  for (int t = 0; t < TT; ++t) {
    const int pr = (t & 1) * 16384;        // consume-parity word offset
    const int pw = ((t + 1) & 1) * 16384;  // store-parity word offset

#define SLOT(G, AXC, AXP, HBK)                                                     \
  {                                                                                \
    XPREF(AXP, (G + 1) & 3);                        /* x for slot j+1 */           \
    if ((G) == 0 && t == 0) { asm volatile("s_waitcnt vmcnt(2)" ::: "memory"); }   \
    else                    { asm volatile("s_waitcnt vmcnt(11)" ::: "memory"); }  \
    __builtin_amdgcn_sched_barrier(0);                                             \
    f32x4 acc[4];                                                                  \
    _Pragma("unroll") for (int g_ = 0; g_ < 4; ++g_) acc[g_] = f32x4{0,0,0,0};     \
    _Pragma("unroll") for (int s_ = 0; s_ < 2; ++s_)                               \
      _Pragma("unroll") for (int g_ = 0; g_ < 4; ++g_)                             \
        acc[g_] = __builtin_amdgcn_mfma_f32_16x16x32_bf16(                         \
            __builtin_bit_cast(bf16x8, AXC[s_]), Wf[s_][g_], acc[g_], 0, 0, 0);    \
    if (t > 0) {                                                                   \
      int bad_;                                                                    \
      VBAD(HBK, bad_);                                                             \
      int rtry_ = 0;                                                               \
      while (__any(bad_ != 0) && ++rtry_ < RETRY_CAP) {                            \
        __builtin_amdgcn_s_sleep(1);                                               \
        HISSUE(HBK, hrb[G] + pr);                                                  \
        asm volatile("s_waitcnt vmcnt(0)" ::: "memory");                           \
        __builtin_amdgcn_sched_barrier(0);                                         \
        VBAD(HBK, bad_);                                                           \
      }                                                                            \
      _Pragma("unroll") for (int s_ = 0; s_ < 4; ++s_) {                           \
        i32x4 fr_;                                                                 \
        fr_[0] = __builtin_amdgcn_perm(HBK[2*s_][1],   HBK[2*s_][0],   0x07060302);\
        fr_[1] = __builtin_amdgcn_perm(HBK[2*s_][3],   HBK[2*s_][2],   0x07060302);\
        fr_[2] = __builtin_amdgcn_perm(HBK[2*s_+1][1], HBK[2*s_+1][0], 0x07060302);\
        fr_[3] = __builtin_amdgcn_perm(HBK[2*s_+1][3], HBK[2*s_+1][2], 0x07060302);\
        _Pragma("unroll") for (int g_ = 0; g_ < 4; ++g_)                           \
          acc[g_] = __builtin_amdgcn_mfma_f32_16x16x32_bf16(                       \
              __builtin_bit_cast(bf16x8, fr_), Rf[s_][g_], acc[g_], 0, 0, 0);      \
      }                                                                            \
    }                                                                              \
    __builtin_amdgcn_sched_barrier(0);                                             \
    /* prefetch h for slot j+2 into the just-freed bank (always: uniform queue) */ \
    {                                                                              \
      const int gc_ = (G + 2) & 3;                                                 \
      const int pc_ = ((G) >= 2) ? (((t + 1) & 1) * 16384) : pr;                   \
      HISSUE(HBK, hrb[gc_] + pc_);                                                 \
    }                                                                              \
    __syncthreads();                                                               \
    _Pragma("unroll") for (int g_ = 0; g_ < 4; ++g_)                               \
      *(f32x4*)&zone[((w * 4 + g_) * 64 + lane) * 4] = acc[g_];                    \
    __syncthreads();                                                               \
    if (gact) {                                                                    \
      const int lsrc_ = (gr >> 2) * 16 + guu, jj_ = gr & 3;                        \
      float z_[4];                                                                 \
      _Pragma("unroll") for (int g_ = 0; g_ < 4; ++g_) {                           \
        float s_ = bv[g_];                                                         \
        _Pragma("unroll") for (int ww_ = 0; ww_ < 8; ++ww_)                        \
          s_ += zone[((ww_ * 4 + g_) * 64 + lsrc_) * 4 + jj_];                     \
        z_[g_] = s_;                                                               \
      }                                                                            \
      const float ig_ = 1.f / (1.f + __expf(-z_[0]));                              \
      const float fg_ = 1.f / (1.f + __expf(-z_[1]));                              \
      const float gt_ = 1.f - 2.f / (1.f + __expf(2.f * z_[2]));                   \
      const float og_ = 1.f / (1.f + __expf(-z_[3]));                              \
      const float c_ = fg_ * cst[G] + ig_ * gt_;                                   \
      cst[G] = c_;                                                                 \
      const float h_ = og_ * (1.f - 2.f / (1.f + __expf(2.f * c_)));               \
      if (t < TT - 1) {                                                            \
        const u32 hw_ = ((u32)f2bf(h_) << 16) | (u32)(t + 1);                      \
        u32* hp_ = hsb[G] + pw;                                                    \
        asm volatile("global_store_dword %0, %1, off sc0 sc1"                      \
                     :: "v"(hp_), "v"(hw_) : "memory");                            \
      } else {                                                                     \
        out[(size_t)((G) * 16 + gr) * UU + u0 + guu] = h_;                         \
      }                                                                            \
    }                                                                              \
  }

    SLOT(0, AxA, AxB, HA)
    SLOT(1, AxB, AxA, HB)
    SLOT(2, AxA, AxB, HA)
    SLOT(3, AxB, AxA, HB)
#undef SLOT
  }
#undef XPREF
#undef HISSUE
#undef VBAD
}

extern "C" void kernel_launch(void* const* d_in, const int* in_sizes, int n_in,
                              void* d_out, int out_size, void* d_ws, size_t ws_size,
                              hipStream_t stream) {
  const float* x = (const float*)d_in[0];
  const float* W = (const float*)d_in[1];
  const float* R = (const float*)d_in[2];
  const float* b = (const float*)d_in[3];
  float* out = (float*)d_out;

  char* ws = (char*)d_ws;
  u16* xb = (u16*)ws;                                // 32 MB
  const size_t XB_BYTES = (size_t)BB * TT * DD * 2;
  u32* hbuf = (u32*)(ws + XB_BYTES);                 // 4*2*16*1024*4 = 512 KB
  const int HB_WORDS = 4 * 2 * 16 * 1024;

  hipLaunchKernelGGL(cvt_x_kernel, dim3((BB * TT * DD / 8 + 255) / 256), dim3(256), 0, stream,
                     x, xb, BB * TT * DD / 8);
  hipLaunchKernelGGL(zero_kernel, dim3(64), dim3(256), 0, stream, hbuf, HB_WORDS);
  hipLaunchKernelGGL(lstm_persist, dim3(64), dim3(512), 0, stream,
                     W, R, b, xb, hbuf, out);
}

// Round 12
// 4792.253 us; speedup vs baseline: 1.1295x; 1.1295x over previous
//
#include <hip/hip_runtime.h>
#include <hip/hip_bf16.h>
#include <stdint.h>

#define BB 64
#define TT 512
#define DD 512
#define UU 1024
#define G4 4096
#define RETRY_CAP 4096
#define ROWSTR 576   // words per row in an h plane (512 data + 64 check/pad)
#define PLANE 9216   // words per (grp,parity) plane = 16*576

typedef __bf16 bf16x8 __attribute__((ext_vector_type(8)));
typedef float f32x4 __attribute__((ext_vector_type(4)));
typedef int i32x4 __attribute__((ext_vector_type(4)));
typedef unsigned int u32;
typedef unsigned short u16;
typedef u16 u16x8 __attribute__((ext_vector_type(8)));

__device__ __forceinline__ u16 f2bf(float f) {
  unsigned u = __builtin_bit_cast(unsigned, f);
  return (u16)((u + 0x7FFFu + ((u >> 16) & 1u)) >> 16);  // RTN-even
}

__global__ void cvt_x_kernel(const float* __restrict__ x, u16* __restrict__ xb, int n8) {
  int i = blockIdx.x * blockDim.x + threadIdx.x;
  if (i >= n8) return;
  const float4* p = reinterpret_cast<const float4*>(x) + (size_t)i * 2;
  float4 a = p[0], b = p[1];
  u16x8 o;
  o[0] = f2bf(a.x); o[1] = f2bf(a.y); o[2] = f2bf(a.z); o[3] = f2bf(a.w);
  o[4] = f2bf(b.x); o[5] = f2bf(b.y); o[6] = f2bf(b.z); o[7] = f2bf(b.w);
  reinterpret_cast<u16x8*>(xb)[i] = o;
}

__global__ void zero_kernel(u32* __restrict__ p, int nwords) {
  for (int i = blockIdx.x * blockDim.x + threadIdx.x; i < nwords; i += gridDim.x * blockDim.x) {
    u32 z = 0u;
    const u32* q = p + i;
    asm volatile("global_store_dword %0, %1, off sc0 sc1" :: "v"(q), "v"(z) : "memory");
  }
}

// ---- persistent LSTM: R11 rotation pipeline + checksum-packed bf16 h ----
// 64 WGs x 512 thr (8 waves). WG owns u [bid*16,+16) for 4 groups x 16 rows.
// h plane per (grp,parity): [16 rows][512 bf16-pair words | 64 check words].
// Check word (per row, per producer WG) = XOR(its 8 data words) ^ (t+1):
// torn/stale reads fail the XOR -> retry; wide stores legal; fire-and-forget
// preserved (no store->flag ordering, no FIFO-drain trap). Consumer dwordx4
// data loads are DIRECT bf16x8 A-frags (no v_perm). All sc0 sc1 (proven).
__launch_bounds__(512, 1)
__global__ void lstm_persist(const float* __restrict__ W, const float* __restrict__ R,
                             const float* __restrict__ bias, const u16* __restrict__ xb,
                             u32* __restrict__ hbuf,  // 8 planes * 9216 words
                             float* __restrict__ out) {
  __shared__ float zone[8 * 4 * 64 * 4];   // [wave][gatefrag][lane][reg] f32, 32 KB
  __shared__ u16 hstage[16][16];           // packed h staging, 512 B

  const int bid = blockIdx.x;
  const int tid = threadIdx.x;
  const int w = tid >> 6, lane = tid & 63, l15 = lane & 15, lk = lane >> 4;
  const int u0 = bid * 16;
  const int gr = w * 2 + ((lane >> 4) & 1);  // gate row (lanes<32)
  const int guu = lane & 15;
  const bool gact = lane < 32;

  // ---- persistent weight fragments (R2/R7/R11-verified layout) ----
  bf16x8 Wf[2][4];  // x: k0 = w*64 + s*32 + lk*8
  bf16x8 Rf[4][4];  // h: k0 = w*128 + s*32 + lk*8
  #pragma unroll
  for (int g = 0; g < 4; ++g) {
    const int gcol = g * 1024 + u0 + l15;
    #pragma unroll
    for (int s = 0; s < 2; ++s) {
      const int k0 = w * 64 + s * 32 + lk * 8;
      u16x8 tmp;
      #pragma unroll
      for (int j = 0; j < 8; ++j) tmp[j] = f2bf(W[(size_t)(k0 + j) * G4 + gcol]);
      Wf[s][g] = __builtin_bit_cast(bf16x8, tmp);
    }
    #pragma unroll
    for (int s = 0; s < 4; ++s) {
      const int k0 = w * 128 + s * 32 + lk * 8;
      u16x8 tmp;
      #pragma unroll
      for (int j = 0; j < 8; ++j) tmp[j] = f2bf(R[(size_t)(k0 + j) * G4 + gcol]);
      Rf[s][g] = __builtin_bit_cast(bf16x8, tmp);
    }
  }
  float bv[4];
  #pragma unroll
  for (int g = 0; g < 4; ++g) bv[g] = bias[g * 1024 + u0 + guu];
  float cst[4] = {0.f, 0.f, 0.f, 0.f};

  // ---- pointers ----
  const u16* xq[4];
  const u32 *hrb[4], *hkb[4];  // consumer: data base, check base (parity 0)
  u32 *hsd[4], *hsc[4];        // producer (lane<2): data, check (parity 0)
  const int prow = w * 2 + (lane & 1);  // producer row (valid for lane<2)
  #pragma unroll
  for (int g = 0; g < 4; ++g) {
    xq[g] = xb + (size_t)(g * 16 + l15) * (TT * DD) + w * 64 + lk * 8;
    hrb[g] = hbuf + (size_t)g * 2 * PLANE + l15 * ROWSTR + w * 64 + lk * 4;
    hkb[g] = hbuf + (size_t)g * 2 * PLANE + l15 * ROWSTR + 512 + ((lk >> 1) & 1) * 32 + w * 4;
    hsd[g] = hbuf + (size_t)g * 2 * PLANE + prow * ROWSTR + bid * 8;
    hsc[g] = hbuf + (size_t)g * 2 * PLANE + prow * ROWSTR + 512 + (bid & 1) * 32 + (bid >> 1);
  }

  asm volatile("s_waitcnt vmcnt(0)" ::: "memory");  // weight loads drained
  __builtin_amdgcn_sched_barrier(0);

  i32x4 HA[4], HB[4];    // h data banks
  i32x4 HCA, HCB;        // h check banks
  i32x4 AxA[2], AxB[2];  // x banks

#define XPREF(AX, GN)                                                    \
  asm volatile(                                                          \
      "global_load_dwordx4 %0, %2, off\n\t"                              \
      "global_load_dwordx4 %1, %2, off offset:64"                        \
      : "=&v"(AX[0]), "=&v"(AX[1]) : "v"(xq[GN]));                       \
  xq[GN] += DD

#define HISSUE(HBK, HCK, DP, CP)                                         \
  asm volatile(                                                          \
      "global_load_dwordx4 %0, %5, off sc0 sc1\n\t"                      \
      "global_load_dwordx4 %1, %5, off offset:64 sc0 sc1\n\t"            \
      "global_load_dwordx4 %2, %5, off offset:128 sc0 sc1\n\t"           \
      "global_load_dwordx4 %3, %5, off offset:192 sc0 sc1\n\t"           \
      "global_load_dwordx4 %4, %6, off sc0 sc1"                          \
      : "=&v"(HBK[0]), "=&v"(HBK[1]), "=&v"(HBK[2]), "=&v"(HBK[3]),      \
        "=&v"(HCK)                                                       \
      : "v"(DP), "v"(CP) : "memory")

#define VBADCK(HBK, HCK, badv)                                           \
  badv = 0;                                                              \
  _Pragma("unroll") for (int s_ = 0; s_ < 4; ++s_) {                     \
    u32 p_ = (u32)HBK[s_][0] ^ (u32)HBK[s_][1] ^ (u32)HBK[s_][2] ^       \
             (u32)HBK[s_][3];                                            \
    p_ ^= (u32)__shfl_xor((int)p_, 16);                                  \
    badv |= (int)(p_ ^ (u32)HCK[s_] ^ (u32)t);                           \
  }

  // prime x for slot 0
  XPREF(AxA, 0);

  #pragma unroll 1
  for (int t = 0; t < TT; ++t) {
    const int pr9 = (t & 1) * PLANE;        // consume-parity word offset
    const int pw9 = ((t + 1) & 1) * PLANE;  // store-parity word offset

#define SLOT(G, AXC, AXP, HBK, HCK)                                                \
  {                                                                                \
    XPREF(AXP, (G + 1) & 3);                                                       \
    if ((G) == 0 && t == 0)      { asm volatile("s_waitcnt vmcnt(2)" ::: "memory"); } \
    else if (t == TT - 1 && (G) > 0) { asm volatile("s_waitcnt vmcnt(7)" ::: "memory"); } \
    else                         { asm volatile("s_waitcnt vmcnt(10)" ::: "memory"); } \
    __builtin_amdgcn_sched_barrier(0);                                             \
    f32x4 acc[4];                                                                  \
    _Pragma("unroll") for (int g_ = 0; g_ < 4; ++g_) acc[g_] = f32x4{0,0,0,0};     \
    _Pragma("unroll") for (int s_ = 0; s_ < 2; ++s_)                               \
      _Pragma("unroll") for (int g_ = 0; g_ < 4; ++g_)                             \
        acc[g_] = __builtin_amdgcn_mfma_f32_16x16x32_bf16(                         \
            __builtin_bit_cast(bf16x8, AXC[s_]), Wf[s_][g_], acc[g_], 0, 0, 0);    \
    if (t > 0) {                                                                   \
      int bad_;                                                                    \
      VBADCK(HBK, HCK, bad_);                                                      \
      int rtry_ = 0;                                                               \
      while (__any(bad_ != 0) && ++rtry_ < RETRY_CAP) {                            \
        __builtin_amdgcn_s_sleep(1);                                               \
        HISSUE(HBK, HCK, hrb[G] + pr9, hkb[G] + pr9);                              \
        asm volatile("s_waitcnt vmcnt(0)" ::: "memory");                           \
        __builtin_amdgcn_sched_barrier(0);                                         \
        VBADCK(HBK, HCK, bad_);                                                    \
      }                                                                            \
      _Pragma("unroll") for (int s_ = 0; s_ < 4; ++s_) {                           \
        _Pragma("unroll") for (int g_ = 0; g_ < 4; ++g_)                           \
          acc[g_] = __builtin_amdgcn_mfma_f32_16x16x32_bf16(                       \
              __builtin_bit_cast(bf16x8, HBK[s_]), Rf[s_][g_], acc[g_], 0, 0, 0);  \
      }                                                                            \
    }                                                                              \
    __builtin_amdgcn_sched_barrier(0);                                             \
    /* prefetch h for slot j+2 into the just-freed bank */                         \
    {                                                                              \
      const int gc_ = (G + 2) & 3;                                                 \
      const int pc9_ = ((G) >= 2) ? (((t + 1) & 1) * PLANE) : pr9;                 \
      HISSUE(HBK, HCK, hrb[gc_] + pc9_, hkb[gc_] + pc9_);                          \
    }                                                                              \
    /* zone writes protected from prev-slot gate reads by prev BAR_C */            \
    _Pragma("unroll") for (int g_ = 0; g_ < 4; ++g_)                               \
      *(f32x4*)&zone[((w * 4 + g_) * 64 + lane) * 4] = acc[g_];                    \
    __syncthreads(); /* BAR_B: zone ready */                                       \
    if (gact) {                                                                    \
      const int lsrc_ = (gr >> 2) * 16 + guu, jj_ = gr & 3;                        \
      float z_[4];                                                                 \
      _Pragma("unroll") for (int g_ = 0; g_ < 4; ++g_) {                           \
        float s_ = bv[g_];                                                         \
        _Pragma("unroll") for (int ww_ = 0; ww_ < 8; ++ww_)                        \
          s_ += zone[((ww_ * 4 + g_) * 64 + lsrc_) * 4 + jj_];                     \
        z_[g_] = s_;                                                               \
      }                                                                            \
      const float ig_ = 1.f / (1.f + __expf(-z_[0]));                              \
      const float fg_ = 1.f / (1.f + __expf(-z_[1]));                              \
      const float gt_ = 1.f - 2.f / (1.f + __expf(2.f * z_[2]));                   \
      const float og_ = 1.f / (1.f + __expf(-z_[3]));                              \
      const float c_ = fg_ * cst[G] + ig_ * gt_;                                   \
      cst[G] = c_;                                                                 \
      const float h_ = og_ * (1.f - 2.f / (1.f + __expf(2.f * c_)));               \
      if (t < TT - 1) hstage[gr][guu] = f2bf(h_);                                  \
      else out[(size_t)((G) * 16 + gr) * UU + u0 + guu] = h_;                      \
    }                                                                              \
    __syncthreads(); /* BAR_C: hstage ready; also fences next zone writes */       \
    if (t < TT - 1) {                                                              \
      if (lane < 2) {                                                              \
        const u32* hp_ = (const u32*)&hstage[prow][0];                             \
        u32 d0_ = hp_[0], d1_ = hp_[1], d2_ = hp_[2], d3_ = hp_[3];                \
        u32 d4_ = hp_[4], d5_ = hp_[5], d6_ = hp_[6], d7_ = hp_[7];                \
        u32 ck_ = d0_ ^ d1_ ^ d2_ ^ d3_ ^ d4_ ^ d5_ ^ d6_ ^ d7_ ^ (u32)(t + 1);    \
        i32x4 lo_{(int)d0_, (int)d1_, (int)d2_, (int)d3_};                         \
        i32x4 hi_{(int)d4_, (int)d5_, (int)d6_, (int)d7_};                         \
        u32* dp_ = hsd[G] + pw9;                                                   \
        u32* cp_ = hsc[G] + pw9;                                                   \
        asm volatile(                                                              \
            "global_store_dwordx4 %0, %1, off sc0 sc1\n\t"                         \
            "global_store_dwordx4 %0, %2, off offset:16 sc0 sc1\n\t"               \
            "global_store_dword %3, %4, off sc0 sc1"                               \
            :: "v"(dp_), "v"(lo_), "v"(hi_), "v"(cp_), "v"(ck_) : "memory");       \
      }                                                                            \
    }                                                                              \
  }

    SLOT(0, AxA, AxB, HA, HCA)
    SLOT(1, AxB, AxA, HB, HCB)
    SLOT(2, AxA, AxB, HA, HCA)
    SLOT(3, AxB, AxA, HB, HCB)
#undef SLOT
  }
#undef XPREF
#undef HISSUE
#undef VBADCK
}

extern "C" void kernel_launch(void* const* d_in, const int* in_sizes, int n_in,
                              void* d_out, int out_size, void* d_ws, size_t ws_size,
                              hipStream_t stream) {
  const float* x = (const float*)d_in[0];
  const float* W = (const float*)d_in[1];
  const float* R = (const float*)d_in[2];
  const float* b = (const float*)d_in[3];
  float* out = (float*)d_out;

  char* ws = (char*)d_ws;
  u16* xb = (u16*)ws;                                // 32 MB
  const size_t XB_BYTES = (size_t)BB * TT * DD * 2;
  u32* hbuf = (u32*)(ws + XB_BYTES);                 // 8 planes * 9216 words = 288 KB
  const int HB_WORDS = 8 * PLANE;

  hipLaunchKernelGGL(cvt_x_kernel, dim3((BB * TT * DD / 8 + 255) / 256), dim3(256), 0, stream,
                     x, xb, BB * TT * DD / 8);
  hipLaunchKernelGGL(zero_kernel, dim3(64), dim3(256), 0, stream, hbuf, HB_WORDS);
  hipLaunchKernelGGL(lstm_persist, dim3(64), dim3(512), 0, stream,
                     W, R, b, xb, hbuf, out);
}

// Round 13
// 4292.925 us; speedup vs baseline: 1.2609x; 1.1163x over previous
//
#include <hip/hip_runtime.h>
#include <hip/hip_bf16.h>
#include <stdint.h>

#define BB 64
#define TT 512
#define DD 512
#define UU 1024
#define G4 4096
#define PLANE_W 8192            // words per (grp,plane): 8 rows * 1024 u
#define GRP_W (3 * PLANE_W)     // 3 planes per grp
#define LRETRY 24
#define GRETRY 4096

typedef __bf16 bf16x8 __attribute__((ext_vector_type(8)));
typedef float f32x4 __attribute__((ext_vector_type(4)));
typedef int i32x4 __attribute__((ext_vector_type(4)));
typedef unsigned int u32;
typedef unsigned short u16;
typedef u16 u16x8 __attribute__((ext_vector_type(8)));

__device__ __forceinline__ u16 f2bf(float f) {
  unsigned u = __builtin_bit_cast(unsigned, f);
  return (u16)((u + 0x7FFFu + ((u >> 16) & 1u)) >> 16);  // RTN-even
}

__global__ void cvt_x_kernel(const float* __restrict__ x, u16* __restrict__ xb, int n8) {
  int i = blockIdx.x * blockDim.x + threadIdx.x;
  if (i >= n8) return;
  const float4* p = reinterpret_cast<const float4*>(x) + (size_t)i * 2;
  float4 a = p[0], b = p[1];
  u16x8 o;
  o[0] = f2bf(a.x); o[1] = f2bf(a.y); o[2] = f2bf(a.z); o[3] = f2bf(a.w);
  o[4] = f2bf(b.x); o[5] = f2bf(b.y); o[6] = f2bf(b.z); o[7] = f2bf(b.w);
  reinterpret_cast<u16x8*>(xb)[i] = o;
}

__global__ void zero_kernel(u32* __restrict__ p, int nwords) {
  for (int i = blockIdx.x * blockDim.x + threadIdx.x; i < nwords; i += gridDim.x * blockDim.x) {
    u32 z = 0u;
    const u32* q = p + i;
    asm volatile("global_store_dword %0, %1, off sc0 sc1" :: "v"(q), "v"(z) : "memory");
  }
}

// ---- persistent LSTM: XCD-closed rows + dual-plane (local L2 / global IC) h ----
// 256 WGs x 512 thr; LDS 88KB forces 1 WG/CU -> 256 WGs fill all 256 CUs.
// grp = bid&7 (XCD under round-robin dispatch [T1]); grp owns batch rows
// [grp*8,+8) END-TO-END: h never needs to leave the XCD. slot = bid>>3 owns
// u [slot*32,+32). Waves (8) k-split: x [w*64,+64), h [w*128,+128).
// Transport: tagged u32 ((bf16<<16)|step), stored to BOTH a local plane (sc0,
// per-XCD L2) and a global plane (sc0 sc1, IC; R7-proven). Consumers read
// local speculatively, validate tags, retry<=24; on failure flip per-WG flag
// and use the global path forever (correct regardless of dispatch topology).
// Triple-buffered planes remove the depth-2 WAR race.
__launch_bounds__(512, 1)
__global__ void lstm_persist(const float* __restrict__ W, const float* __restrict__ R,
                             const float* __restrict__ bias, const u16* __restrict__ xb,
                             u32* __restrict__ hL, u32* __restrict__ hG,
                             float* __restrict__ out) {
  __shared__ float zone[8 * 8 * 64 * 4];  // 64 KB: [wave][f][lane][reg]
  __shared__ float ballast[6144];         // 24 KB occupancy ballast (1 WG/CU)
  __shared__ int uglob;

  const int tid = threadIdx.x;
  const int w = tid >> 6, lane = tid & 63, l15 = lane & 15, lk = lane >> 4;
  const int grp = blockIdx.x & 7;
  const int slot = blockIdx.x >> 3;
  const int u0 = slot * 32;
  const int row8 = l15 & 7;

  if (tid == 0) uglob = 0;
  if (tid == 99999) ballast[0] = 1.f;  // keep ballast allocated

  // ---- persistent weight fragments (R2/R7-verified layout), u-width 32 ----
  bf16x8 Wf[2][8];  // x: k0 = w*64 + s*32 + lk*8
  bf16x8 Rf[4][8];  // h: k0 = w*128 + s*32 + lk*8
  #pragma unroll
  for (int f = 0; f < 8; ++f) {
    const int gcol = (f >> 1) * 1024 + u0 + (f & 1) * 16 + l15;
    #pragma unroll
    for (int s = 0; s < 2; ++s) {
      const int k0 = w * 64 + s * 32 + lk * 8;
      u16x8 tmp;
      #pragma unroll
      for (int j = 0; j < 8; ++j) tmp[j] = f2bf(W[(size_t)(k0 + j) * G4 + gcol]);
      Wf[s][f] = __builtin_bit_cast(bf16x8, tmp);
    }
    #pragma unroll
    for (int s = 0; s < 4; ++s) {
      const int k0 = w * 128 + s * 32 + lk * 8;
      u16x8 tmp;
      #pragma unroll
      for (int j = 0; j < 8; ++j) tmp[j] = f2bf(R[(size_t)(k0 + j) * G4 + gcol]);
      Rf[s][f] = __builtin_bit_cast(bf16x8, tmp);
    }
  }
  const int grow = tid >> 5, guu = tid & 31;  // gate ownership (tid<256)
  float bv[4];
  #pragma unroll
  for (int g = 0; g < 4; ++g) bv[g] = bias[g * 1024 + u0 + guu];
  float cst = 0.f;

  // ---- pointers ----
  const u16* xp = xb + (size_t)(grp * 8 + row8) * (TT * DD) + w * 64 + lk * 8;
  const u32* hlc = hL + (size_t)grp * GRP_W + row8 * 1024 + w * 128 + lk * 8;
  const u32* hgc = hG + (size_t)grp * GRP_W + row8 * 1024 + w * 128 + lk * 8;
  u32* hlp = hL + (size_t)grp * GRP_W + grow * 1024 + u0 + guu;  // valid tid<256
  u32* hgp = hG + (size_t)grp * GRP_W + grow * 1024 + u0 + guu;

  asm volatile("s_waitcnt vmcnt(0)" ::: "memory");
  __syncthreads();  // uglob visible; weights loaded

  i32x4 H[4][2];

#define HISSUE_L(BASE)                                                   \
  asm volatile(                                                          \
      "global_load_dwordx4 %0, %8, off sc0\n\t"                          \
      "global_load_dwordx4 %1, %8, off offset:16 sc0\n\t"                \
      "global_load_dwordx4 %2, %8, off offset:128 sc0\n\t"               \
      "global_load_dwordx4 %3, %8, off offset:144 sc0\n\t"               \
      "global_load_dwordx4 %4, %8, off offset:256 sc0\n\t"               \
      "global_load_dwordx4 %5, %8, off offset:272 sc0\n\t"               \
      "global_load_dwordx4 %6, %8, off offset:384 sc0\n\t"               \
      "global_load_dwordx4 %7, %8, off offset:400 sc0"                   \
      : "=&v"(H[0][0]), "=&v"(H[0][1]), "=&v"(H[1][0]), "=&v"(H[1][1]),  \
        "=&v"(H[2][0]), "=&v"(H[2][1]), "=&v"(H[3][0]), "=&v"(H[3][1])   \
      : "v"(BASE) : "memory")

#define HISSUE_G(BASE)                                                   \
  asm volatile(                                                          \
      "global_load_dwordx4 %0, %8, off sc0 sc1\n\t"                      \
      "global_load_dwordx4 %1, %8, off offset:16 sc0 sc1\n\t"            \
      "global_load_dwordx4 %2, %8, off offset:128 sc0 sc1\n\t"           \
      "global_load_dwordx4 %3, %8, off offset:144 sc0 sc1\n\t"           \
      "global_load_dwordx4 %4, %8, off offset:256 sc0 sc1\n\t"           \
      "global_load_dwordx4 %5, %8, off offset:272 sc0 sc1\n\t"           \
      "global_load_dwordx4 %6, %8, off offset:384 sc0 sc1\n\t"           \
      "global_load_dwordx4 %7, %8, off offset:400 sc0 sc1"               \
      : "=&v"(H[0][0]), "=&v"(H[0][1]), "=&v"(H[1][0]), "=&v"(H[1][1]),  \
        "=&v"(H[2][0]), "=&v"(H[2][1]), "=&v"(H[3][0]), "=&v"(H[3][1])   \
      : "v"(BASE) : "memory")

#define VBAD(badv)                                                       \
  badv = 0;                                                              \
  _Pragma("unroll") for (int s_ = 0; s_ < 4; ++s_)                       \
    _Pragma("unroll") for (int q_ = 0; q_ < 2; ++q_)                     \
      _Pragma("unroll") for (int d_ = 0; d_ < 4; ++d_)                   \
        badv |= (H[s_][q_][d_] ^ t) & 0xFFFF

  int pc = 0;  // plane index t % 3
  #pragma unroll 1
  for (int t = 0; t < TT; ++t) {
    const int pn = (pc == 2) ? 0 : pc + 1;

    // x loads first in queue (so vmcnt(8) drains them, not h)
    i32x4 Ax[2];
    asm volatile(
        "global_load_dwordx4 %0, %2, off\n\t"
        "global_load_dwordx4 %1, %2, off offset:64"
        : "=&v"(Ax[0]), "=&v"(Ax[1]) : "v"(xp));
    xp += DD;

    const u32* lq = hlc + pc * PLANE_W;
    const u32* gq = hgc + pc * PLANE_W;
    const int ug = uglob;
    if (!ug) { HISSUE_L(lq); } else { HISSUE_G(gq); }

    asm volatile("s_waitcnt vmcnt(8)" ::: "memory");  // x (and older stores) done
    __builtin_amdgcn_sched_barrier(0);

    f32x4 acc[8];
    #pragma unroll
    for (int f = 0; f < 8; ++f) acc[f] = f32x4{0.f, 0.f, 0.f, 0.f};

    #pragma unroll
    for (int s = 0; s < 2; ++s)
      #pragma unroll
      for (int f = 0; f < 8; ++f)
        acc[f] = __builtin_amdgcn_mfma_f32_16x16x32_bf16(
            __builtin_bit_cast(bf16x8, Ax[s]), Wf[s][f], acc[f], 0, 0, 0);

    asm volatile("s_waitcnt vmcnt(0)" ::: "memory");  // h landed
    __builtin_amdgcn_sched_barrier(0);

    if (t > 0) {
      int bad;
      VBAD(bad);
      if (!ug) {
        int rl = 0;
        while (__any(bad != 0) && ++rl <= LRETRY) {
          HISSUE_L(lq);
          asm volatile("s_waitcnt vmcnt(0)" ::: "memory");
          __builtin_amdgcn_sched_barrier(0);
          VBAD(bad);
        }
        if (__any(bad != 0)) uglob = 1;  // local transport broken -> global forever
      }
      int rg = 0;
      while (__any(bad != 0) && ++rg < GRETRY) {
        __builtin_amdgcn_s_sleep(2);
        HISSUE_G(gq);
        asm volatile("s_waitcnt vmcnt(0)" ::: "memory");
        __builtin_amdgcn_sched_barrier(0);
        VBAD(bad);
      }
      // h-part MFMA (payload = hi16, R7-verified perm unpack)
      #pragma unroll
      for (int s = 0; s < 4; ++s) {
        i32x4 fr;
        fr[0] = __builtin_amdgcn_perm(H[s][0][1], H[s][0][0], 0x07060302);
        fr[1] = __builtin_amdgcn_perm(H[s][0][3], H[s][0][2], 0x07060302);
        fr[2] = __builtin_amdgcn_perm(H[s][1][1], H[s][1][0], 0x07060302);
        fr[3] = __builtin_amdgcn_perm(H[s][1][3], H[s][1][2], 0x07060302);
        #pragma unroll
        for (int f = 0; f < 8; ++f)
          acc[f] = __builtin_amdgcn_mfma_f32_16x16x32_bf16(
              __builtin_bit_cast(bf16x8, fr), Rf[s][f], acc[f], 0, 0, 0);
      }
    }

    // ---- k-split exchange ----
    __syncthreads();  // WAR vs previous step's gate reads
    #pragma unroll
    for (int f = 0; f < 8; ++f)
      *(f32x4*)&zone[((w * 8 + f) * 64 + lane) * 4] = acc[f];
    __syncthreads();

    // ---- gates: thread tid<256 owns (row=grow, u=u0+guu) ----
    if (tid < 256) {
      float z[4];
      #pragma unroll
      for (int g = 0; g < 4; ++g) {
        const int f = g * 2 + (guu >> 4);
        const int zidx = (f * 64 + (grow >> 2) * 16 + (guu & 15)) * 4 + (grow & 3);
        float s = bv[g];
        #pragma unroll
        for (int ww = 0; ww < 8; ++ww) s += zone[(ww * 8) * 256 + zidx];
        z[g] = s;
      }
      const float ig = 1.f / (1.f + __expf(-z[0]));
      const float fg = 1.f / (1.f + __expf(-z[1]));
      const float gt = 1.f - 2.f / (1.f + __expf(2.f * z[2]));  // tanh
      const float og = 1.f / (1.f + __expf(-z[3]));
      const float c = fg * cst + ig * gt;
      cst = c;
      const float h = og * (1.f - 2.f / (1.f + __expf(2.f * c)));

      if (t < TT - 1) {
        const u32 hw = ((u32)f2bf(h) << 16) | (u32)(t + 1);
        u32* lp = hlp + pn * PLANE_W;
        u32* gp = hgp + pn * PLANE_W;
        asm volatile(
            "global_store_dword %0, %2, off sc0\n\t"
            "global_store_dword %1, %2, off sc0 sc1"
            :: "v"(lp), "v"(gp), "v"(hw) : "memory");
      } else {
        out[(size_t)(grp * 8 + grow) * UU + u0 + guu] = h;
      }
    }
    pc = pn;
  }
#undef HISSUE_L
#undef HISSUE_G
#undef VBAD
}

extern "C" void kernel_launch(void* const* d_in, const int* in_sizes, int n_in,
                              void* d_out, int out_size, void* d_ws, size_t ws_size,
                              hipStream_t stream) {
  const float* x = (const float*)d_in[0];
  const float* W = (const float*)d_in[1];
  const float* R = (const float*)d_in[2];
  const float* b = (const float*)d_in[3];
  float* out = (float*)d_out;

  char* ws = (char*)d_ws;
  u16* xb = (u16*)ws;                                  // 32 MB
  const size_t XB_BYTES = (size_t)BB * TT * DD * 2;
  u32* hL = (u32*)(ws + XB_BYTES);                     // 8*3*8192 w = 786 KB
  const int HL_WORDS = 8 * GRP_W;
  u32* hG = hL + HL_WORDS;                             // 786 KB
  const int HZ_WORDS = 2 * HL_WORDS;

  hipLaunchKernelGGL(cvt_x_kernel, dim3((BB * TT * DD / 8 + 255) / 256), dim3(256), 0, stream,
                     x, xb, BB * TT * DD / 8);
  hipLaunchKernelGGL(zero_kernel, dim3(256), dim3(256), 0, stream, hL, HZ_WORDS);
  hipLaunchKernelGGL(lstm_persist, dim3(256), dim3(512), 0, stream,
                     W, R, b, xb, hL, hG, out);
}